// Round 11
// baseline (29.102 us; speedup 1.0000x reference)
//
#include <hip/hip_runtime.h>
#include <math.h>

#define D_MODEL 128
#define D_STATE 64
#define VOCAB 2000
#define SEQ_L 4096
#define BATCH 32
#define BGRP 2                   // batch rows per reduce block (Wv reuse)
#define NBG (BATCH / BGRP)       // 16
#define JSPLIT 64                // chunks per batch row
#define CHUNK (SEQ_L / JSPLIT)   // 64 j's per chunk
#define SEG 32                   // weights: j's per block (16 per half)
#define SEGH 16
#define LN_BLOCKS (VOCAB / 4)    // 500
#define W_BLOCKS (SEQ_L / SEG)   // 128 (blocks 500..627)
#define LN_EPS 1e-5f

static __device__ __forceinline__ void fma4(float4& a, const float4 e, const float4 w) {
  a.x = fmaf(e.x, w.x, a.x);
  a.y = fmaf(e.y, w.y, a.y);
  a.z = fmaf(e.z, w.z, a.z);
  a.w = fmaf(e.w, w.w, a.w);
}

// ============ Kernel 1: fused prep (LN-embed ∥ pooled-conv weights) =========
__global__ __launch_bounds__(256) void prep_kernel(
    const float* __restrict__ emb, const float* __restrict__ ln_w,
    const float* __restrict__ ln_b, const float* __restrict__ A_log,
    const float* __restrict__ Dp, const float* __restrict__ C_re,
    const float* __restrict__ log_dt, float* __restrict__ e_ln,
    float* __restrict__ Wv) {
  if (blockIdx.x < LN_BLOCKS) {
    int v = blockIdx.x * 4 + (threadIdx.x >> 6);
    int t = threadIdx.x & 63;
    const float* row = emb + v * D_MODEL;
    float h0 = row[t];
    float h1 = row[t + 64];
    float s = h0 + h1;
#pragma unroll
    for (int off = 32; off; off >>= 1) s += __shfl_xor(s, off);
    float mu = s * (1.0f / D_MODEL);
    float d0 = h0 - mu, d1 = h1 - mu;
    float q = d0 * d0 + d1 * d1;
#pragma unroll
    for (int off = 32; off; off >>= 1) q += __shfl_xor(q, off);
    float var = q * (1.0f / D_MODEL);
    float rs = rsqrtf(var + LN_EPS);
    e_ln[v * D_MODEL + t]      = d0 * rs * ln_w[t]      + ln_b[t];
    e_ln[v * D_MODEL + t + 64] = d1 * rs * ln_w[t + 64] + ln_b[t + 64];
  } else {
    __shared__ float Ash[D_STATE];
    if (threadIdx.x < D_STATE) Ash[threadIdx.x] = -expf(A_log[threadIdx.x]);
    __syncthreads();
    int wb = blockIdx.x - LN_BLOCKS;
    int m = threadIdx.x & (D_MODEL - 1);
    int sub = threadIdx.x >> 7;               // 0 or 1
    int j0 = wb * SEG + sub * SEGH;
    float acc[SEGH];
#pragma unroll
    for (int k = 0; k < SEGH; ++k) acc[k] = 0.0f;
    float dt = expf(log_dt[m]);
    float bs = 0.0f;
    float r1_end = (float)(SEQ_L - j0 - (SEGH - 1));
    for (int n = 0; n < D_STATE; ++n) {
      float x = dt * Ash[n];                  // negative
      float q = expf(x);
      float r = C_re[m * D_STATE + n] / (1.0f - q);
      bs += r;
      float g = expf(x * r1_end);             // q^{L - j0 - 15}
      acc[SEGH - 1] += r * g;
#pragma unroll
      for (int jj = SEGH - 2; jj >= 0; --jj) {
        g *= q;
        acc[jj] += r * g;
      }
    }
    float base = Dp[m] + bs;
#pragma unroll
    for (int k = 0; k < SEGH; ++k)
      Wv[(j0 + k) * D_MODEL + m] = base - acc[k];
  }
}

// ============ Kernel 2: float4 gather-reduce + in-block classifier ==========
// Block (bg, s), 128 thr: mq = tid&31 owns m = mq*4..mq*4+3 (float4 columns),
// jq = tid>>5 owns 16 of the 64 j's. For 2 batch rows (Wv loaded once):
//   p_b[m4] = sum_j e_ln4[x[b,j]][mq] * Wv4[j][mq]
//   pc[(b*JSPLIT+s)*2+c] = sum over block of dot4(p_b, W_cls4[c])
__global__ __launch_bounds__(128) void reduce_kernel(
    const int* __restrict__ x, const float* __restrict__ e_ln,
    const float* __restrict__ Wv, const float* __restrict__ W_cls,
    float* __restrict__ pc) {
  __shared__ int toks[BGRP][CHUNK];
  __shared__ float sm[2][4];
  int bg = blockIdx.x;
  int sIdx = blockIdx.y;
  int tid = threadIdx.x;
  if (tid < CHUNK) {
    toks[0][tid] = x[(bg * BGRP + 0) * SEQ_L + sIdx * CHUNK + tid];
  } else {
    toks[1][tid - CHUNK] = x[(bg * BGRP + 1) * SEQ_L + sIdx * CHUNK + (tid - CHUNK)];
  }
  __syncthreads();
  int mq = tid & 31;               // float4 column group
  int jq = tid >> 5;               // 0..3
  const float4* e4  = (const float4*)e_ln;
  const float4* w4  = (const float4*)Wv;
  const float4* wc4 = (const float4*)W_cls;
  float4 a0 = {0,0,0,0}, a1 = {0,0,0,0};   // row 0, ILP pair
  float4 c0 = {0,0,0,0}, c1 = {0,0,0,0};   // row 1, ILP pair
  int jb = jq * 16;
  const float4* wrow = w4 + (sIdx * CHUNK + jb) * 32 + mq;
#pragma unroll
  for (int k = 0; k < 16; k += 2) {
    int ta0 = toks[0][jb + k], ta1 = toks[0][jb + k + 1];
    int tb0 = toks[1][jb + k], tb1 = toks[1][jb + k + 1];
    float4 w_0 = wrow[(k + 0) * 32];
    float4 w_1 = wrow[(k + 1) * 32];
    float4 e00 = e4[ta0 * 32 + mq];
    float4 e01 = e4[ta1 * 32 + mq];
    float4 e10 = e4[tb0 * 32 + mq];
    float4 e11 = e4[tb1 * 32 + mq];
    fma4(a0, e00, w_0);
    fma4(a1, e01, w_1);
    fma4(c0, e10, w_0);
    fma4(c1, e11, w_1);
  }
  float4 p0, p1;
  p0.x = a0.x + a1.x; p0.y = a0.y + a1.y; p0.z = a0.z + a1.z; p0.w = a0.w + a1.w;
  p1.x = c0.x + c1.x; p1.y = c0.y + c1.y; p1.z = c0.z + c1.z; p1.w = c0.w + c1.w;
  float4 wc0 = wc4[mq];
  float4 wc1 = wc4[32 + mq];
  float v00 = p0.x * wc0.x + p0.y * wc0.y + p0.z * wc0.z + p0.w * wc0.w;
  float v01 = p0.x * wc1.x + p0.y * wc1.y + p0.z * wc1.z + p0.w * wc1.w;
  float v10 = p1.x * wc0.x + p1.y * wc0.y + p1.z * wc0.z + p1.w * wc0.w;
  float v11 = p1.x * wc1.x + p1.y * wc1.y + p1.z * wc1.z + p1.w * wc1.w;
#pragma unroll
  for (int off = 32; off; off >>= 1) {
    v00 += __shfl_xor(v00, off);
    v01 += __shfl_xor(v01, off);
    v10 += __shfl_xor(v10, off);
    v11 += __shfl_xor(v11, off);
  }
  int wave = tid >> 6;
  if ((tid & 63) == 0) {
    sm[wave][0] = v00; sm[wave][1] = v01;
    sm[wave][2] = v10; sm[wave][3] = v11;
  }
  __syncthreads();
  if (tid == 0) {
    int b0 = bg * BGRP;
    pc[((b0 + 0) * JSPLIT + sIdx) * 2 + 0] = sm[0][0] + sm[1][0];
    pc[((b0 + 0) * JSPLIT + sIdx) * 2 + 1] = sm[0][1] + sm[1][1];
    pc[((b0 + 1) * JSPLIT + sIdx) * 2 + 0] = sm[0][2] + sm[1][2];
    pc[((b0 + 1) * JSPLIT + sIdx) * 2 + 1] = sm[0][3] + sm[1][3];
  }
}

// ============ Kernel 3: final combine (one block, single writer) ============
__global__ __launch_bounds__(1024) void final_kernel(
    const float* __restrict__ pc, const float* __restrict__ b_cls,
    float* __restrict__ out) {
  int tid = threadIdx.x;
  int b = tid >> 5;                // 0..31
  int k = tid & 31;                // 0..31
  float v0 = pc[(b * JSPLIT + k) * 2 + 0] + pc[(b * JSPLIT + k + 32) * 2 + 0];
  float v1 = pc[(b * JSPLIT + k) * 2 + 1] + pc[(b * JSPLIT + k + 32) * 2 + 1];
#pragma unroll
  for (int off = 16; off; off >>= 1) {
    v0 += __shfl_xor(v0, off);     // stays within the 32-lane b-group
    v1 += __shfl_xor(v1, off);
  }
  if (k == 0) {
    out[b * 2 + 0] = v0 * (1.0f / SEQ_L) + b_cls[0];
    out[b * 2 + 1] = v1 * (1.0f / SEQ_L) + b_cls[1];
  }
}

extern "C" void kernel_launch(void* const* d_in, const int* in_sizes, int n_in,
                              void* d_out, int out_size, void* d_ws, size_t ws_size,
                              hipStream_t stream) {
  const int*   x      = (const int*)d_in[0];
  const float* emb    = (const float*)d_in[1];
  const float* ln_w   = (const float*)d_in[2];
  const float* ln_b   = (const float*)d_in[3];
  const float* A_log  = (const float*)d_in[4];
  const float* Dp     = (const float*)d_in[5];
  const float* C_re   = (const float*)d_in[6];
  const float* log_dt = (const float*)d_in[7];
  const float* W_cls  = (const float*)d_in[8];
  const float* b_cls  = (const float*)d_in[9];
  float* out = (float*)d_out;

  char* ws = (char*)d_ws;
  float* e_ln = (float*)(ws);                 // 2000*128*4 = 1,024,000 B
  float* Wv   = (float*)(ws + 1048576);       // 4096*128*4 = 2,097,152 B
  float* pc   = (float*)(ws + 3145728);       // 32*64*2*4  = 16,384 B

  prep_kernel<<<LN_BLOCKS + W_BLOCKS, 256, 0, stream>>>(
      emb, ln_w, ln_b, A_log, Dp, C_re, log_dt, e_ln, Wv);
  reduce_kernel<<<dim3(NBG, JSPLIT), 128, 0, stream>>>(
      x, e_ln, Wv, W_cls, pc);
  final_kernel<<<1, 1024, 0, stream>>>(pc, b_cls, out);
}

// Round 12
// 28.531 us; speedup vs baseline: 1.0200x; 1.0200x over previous
//
#include <hip/hip_runtime.h>
#include <math.h>

#define D_MODEL 128
#define D_STATE 64
#define VOCAB 2000
#define SEQ_L 4096
#define BATCH 32
#define BGRP 2                   // batch rows per reduce block (Wv reuse)
#define NBG (BATCH / BGRP)       // 16
#define JSPLIT 64                // chunks per batch row
#define CHUNK (SEQ_L / JSPLIT)   // 64 j's per chunk
#define SEG 32                   // weights: j's per block (16 per half)
#define SEGH 16
#define LN_BLOCKS (VOCAB / 4)    // 500
#define W_BLOCKS (SEQ_L / SEG)   // 128 (blocks 500..627)
#define LN_EPS 1e-5f

// ============ Kernel 1: fused prep (LN-embed ∥ pooled-conv weights) =========
__global__ __launch_bounds__(256) void prep_kernel(
    const float* __restrict__ emb, const float* __restrict__ ln_w,
    const float* __restrict__ ln_b, const float* __restrict__ A_log,
    const float* __restrict__ Dp, const float* __restrict__ C_re,
    const float* __restrict__ log_dt, float* __restrict__ e_ln,
    float* __restrict__ Wv) {
  if (blockIdx.x < LN_BLOCKS) {
    int v = blockIdx.x * 4 + (threadIdx.x >> 6);
    int t = threadIdx.x & 63;
    const float* row = emb + v * D_MODEL;
    float h0 = row[t];
    float h1 = row[t + 64];
    float s = h0 + h1;
#pragma unroll
    for (int off = 32; off; off >>= 1) s += __shfl_xor(s, off);
    float mu = s * (1.0f / D_MODEL);
    float d0 = h0 - mu, d1 = h1 - mu;
    float q = d0 * d0 + d1 * d1;
#pragma unroll
    for (int off = 32; off; off >>= 1) q += __shfl_xor(q, off);
    float var = q * (1.0f / D_MODEL);
    float rs = rsqrtf(var + LN_EPS);
    e_ln[v * D_MODEL + t]      = d0 * rs * ln_w[t]      + ln_b[t];
    e_ln[v * D_MODEL + t + 64] = d1 * rs * ln_w[t + 64] + ln_b[t + 64];
  } else {
    __shared__ float Ash[D_STATE];
    if (threadIdx.x < D_STATE) Ash[threadIdx.x] = -expf(A_log[threadIdx.x]);
    __syncthreads();
    int wb = blockIdx.x - LN_BLOCKS;
    int m = threadIdx.x & (D_MODEL - 1);
    int sub = threadIdx.x >> 7;               // 0 or 1
    int j0 = wb * SEG + sub * SEGH;
    float acc[SEGH];
#pragma unroll
    for (int k = 0; k < SEGH; ++k) acc[k] = 0.0f;
    float dt = expf(log_dt[m]);
    float bs = 0.0f;
    float r1_end = (float)(SEQ_L - j0 - (SEGH - 1));
    for (int n = 0; n < D_STATE; ++n) {
      float x = dt * Ash[n];                  // negative
      float q = expf(x);
      float r = C_re[m * D_STATE + n] / (1.0f - q);
      bs += r;
      float g = expf(x * r1_end);             // q^{L - j0 - 15}
      acc[SEGH - 1] += r * g;
#pragma unroll
      for (int jj = SEGH - 2; jj >= 0; --jj) {
        g *= q;
        acc[jj] += r * g;
      }
    }
    float base = Dp[m] + bs;
#pragma unroll
    for (int k = 0; k < SEGH; ++k)
      Wv[(j0 + k) * D_MODEL + m] = base - acc[k];
  }
}

// ============ Kernel 2: gather-reduce + in-block classifier =================
// Block (bg, s), 128 thr (tid = m): for 2 batch rows (Wv loaded once),
// 4-deep j-unroll with 8 independent FMA chains (12 outstanding loads/iter).
__global__ __launch_bounds__(128) void reduce_kernel(
    const int* __restrict__ x, const float* __restrict__ e_ln,
    const float* __restrict__ Wv, const float* __restrict__ W_cls,
    float* __restrict__ pc) {
  __shared__ int toks[BGRP][CHUNK];
  __shared__ float sm[2][4];
  int bg = blockIdx.x;
  int sIdx = blockIdx.y;
  int tid = threadIdx.x;           // = m, 0..127
  if (tid < CHUNK) {
    toks[0][tid] = x[(bg * BGRP + 0) * SEQ_L + sIdx * CHUNK + tid];
  } else {
    toks[1][tid - CHUNK] = x[(bg * BGRP + 1) * SEQ_L + sIdx * CHUNK + (tid - CHUNK)];
  }
  __syncthreads();
  int m = tid;
  const float* wbase = Wv + (sIdx * CHUNK) * D_MODEL + m;
  float a00 = 0.0f, a01 = 0.0f, a02 = 0.0f, a03 = 0.0f;   // row 0 chains
  float a10 = 0.0f, a11 = 0.0f, a12 = 0.0f, a13 = 0.0f;   // row 1 chains
#pragma unroll
  for (int j = 0; j < CHUNK; j += 4) {
    int t00 = toks[0][j], t01 = toks[0][j + 1], t02 = toks[0][j + 2], t03 = toks[0][j + 3];
    int t10 = toks[1][j], t11 = toks[1][j + 1], t12 = toks[1][j + 2], t13 = toks[1][j + 3];
    float w0 = wbase[(j + 0) * D_MODEL];
    float w1 = wbase[(j + 1) * D_MODEL];
    float w2 = wbase[(j + 2) * D_MODEL];
    float w3 = wbase[(j + 3) * D_MODEL];
    float e00 = e_ln[t00 * D_MODEL + m];
    float e01 = e_ln[t01 * D_MODEL + m];
    float e02 = e_ln[t02 * D_MODEL + m];
    float e03 = e_ln[t03 * D_MODEL + m];
    float e10 = e_ln[t10 * D_MODEL + m];
    float e11 = e_ln[t11 * D_MODEL + m];
    float e12 = e_ln[t12 * D_MODEL + m];
    float e13 = e_ln[t13 * D_MODEL + m];
    a00 = fmaf(e00, w0, a00);
    a01 = fmaf(e01, w1, a01);
    a02 = fmaf(e02, w2, a02);
    a03 = fmaf(e03, w3, a03);
    a10 = fmaf(e10, w0, a10);
    a11 = fmaf(e11, w1, a11);
    a12 = fmaf(e12, w2, a12);
    a13 = fmaf(e13, w3, a13);
  }
  float p0 = (a00 + a01) + (a02 + a03);
  float p1 = (a10 + a11) + (a12 + a13);
  float wc0 = W_cls[m], wc1 = W_cls[D_MODEL + m];
  float v00 = p0 * wc0, v01 = p0 * wc1;
  float v10 = p1 * wc0, v11 = p1 * wc1;
#pragma unroll
  for (int off = 32; off; off >>= 1) {
    v00 += __shfl_xor(v00, off);
    v01 += __shfl_xor(v01, off);
    v10 += __shfl_xor(v10, off);
    v11 += __shfl_xor(v11, off);
  }
  int wave = tid >> 6;
  if ((tid & 63) == 0) {
    sm[wave][0] = v00; sm[wave][1] = v01;
    sm[wave][2] = v10; sm[wave][3] = v11;
  }
  __syncthreads();
  if (tid == 0) {
    int b0 = bg * BGRP;
    pc[((b0 + 0) * JSPLIT + sIdx) * 2 + 0] = sm[0][0] + sm[1][0];
    pc[((b0 + 0) * JSPLIT + sIdx) * 2 + 1] = sm[0][1] + sm[1][1];
    pc[((b0 + 1) * JSPLIT + sIdx) * 2 + 0] = sm[0][2] + sm[1][2];
    pc[((b0 + 1) * JSPLIT + sIdx) * 2 + 1] = sm[0][3] + sm[1][3];
  }
}

// ============ Kernel 3: final combine (one block, single writer) ============
__global__ __launch_bounds__(1024) void final_kernel(
    const float* __restrict__ pc, const float* __restrict__ b_cls,
    float* __restrict__ out) {
  int tid = threadIdx.x;
  int b = tid >> 5;                // 0..31
  int k = tid & 31;                // 0..31
  float v0 = pc[(b * JSPLIT + k) * 2 + 0] + pc[(b * JSPLIT + k + 32) * 2 + 0];
  float v1 = pc[(b * JSPLIT + k) * 2 + 1] + pc[(b * JSPLIT + k + 32) * 2 + 1];
#pragma unroll
  for (int off = 16; off; off >>= 1) {
    v0 += __shfl_xor(v0, off);     // stays within the 32-lane b-group
    v1 += __shfl_xor(v1, off);
  }
  if (k == 0) {
    out[b * 2 + 0] = v0 * (1.0f / SEQ_L) + b_cls[0];
    out[b * 2 + 1] = v1 * (1.0f / SEQ_L) + b_cls[1];
  }
}

extern "C" void kernel_launch(void* const* d_in, const int* in_sizes, int n_in,
                              void* d_out, int out_size, void* d_ws, size_t ws_size,
                              hipStream_t stream) {
  const int*   x      = (const int*)d_in[0];
  const float* emb    = (const float*)d_in[1];
  const float* ln_w   = (const float*)d_in[2];
  const float* ln_b   = (const float*)d_in[3];
  const float* A_log  = (const float*)d_in[4];
  const float* Dp     = (const float*)d_in[5];
  const float* C_re   = (const float*)d_in[6];
  const float* log_dt = (const float*)d_in[7];
  const float* W_cls  = (const float*)d_in[8];
  const float* b_cls  = (const float*)d_in[9];
  float* out = (float*)d_out;

  char* ws = (char*)d_ws;
  float* e_ln = (float*)(ws);                 // 2000*128*4 = 1,024,000 B
  float* Wv   = (float*)(ws + 1048576);       // 4096*128*4 = 2,097,152 B
  float* pc   = (float*)(ws + 3145728);       // 32*64*2*4  = 16,384 B

  prep_kernel<<<LN_BLOCKS + W_BLOCKS, 256, 0, stream>>>(
      emb, ln_w, ln_b, A_log, Dp, C_re, log_dt, e_ln, Wv);
  reduce_kernel<<<dim3(NBG, JSPLIT), 128, 0, stream>>>(
      x, e_ln, Wv, W_cls, pc);
  final_kernel<<<1, 1024, 0, stream>>>(pc, b_cls, out);
}